// Round 3
// baseline (86.677 us; speedup 1.0000x reference)
//
#include <hip/hip_runtime.h>
#include <math.h>

#define T_IN   2048
#define T_OUT  2276
#define NTH    512
#define CHUNK  5               // 512*5 = 2560 >= 2276
#define NWAVE  (NTH/64)
#define RATE   0.9f

typedef float v4f __attribute__((ext_vector_type(4)));

// LDS layout: THREE float planes (conflict-free b32 reads; the old float2 uv
// plane caused ~4-way bank conflicts on ds_read_b64 at lane stride 4.5):
//   [ur: 2052][ui: 2052][nr: 2052] floats.
// Output staging ALIASES this region (re-used only after the post-scan barrier).
#define NFR     2052           // frames 0..2048 used; pad to multiple of 4
#define ST_N    2304           // staging length per plane (>= T_OUT, 16B aligned)
#define SMEM_B  (3*NFR*4)      // 24624 B -> 4 blocks/CU -> 32 waves/CU

__global__ __launch_bounds__(NTH, 8)
void phase_vocoder_kernel(const float* __restrict__ xr,
                          const float* __restrict__ xi,
                          float* __restrict__ out,
                          int n_rows, long long out_floats)
{
    __shared__ __align__(16) float smem[3 * NFR];
    __shared__ float2 wtot[NWAVE];
    float* ur  = smem;                 // unit-vector real, per input frame
    float* uim = smem + NFR;           // unit-vector imag
    float* nr  = smem + 2 * NFR;       // magnitude
    float* st_re = smem;               // aliases planes after the scan barrier
    float* st_im = smem + ST_N;

    const int row  = blockIdx.x;
    const int tid  = threadIdx.x;
    const int lane = tid & 63;
    const int wid  = tid >> 6;

    // ---- Fill: unit vector + |s| per input frame (float4 loads, b128 LDS writes) ----
    {
        const float4 r = ((const float4*)(xr + (size_t)row * T_IN))[tid];
        const float4 m = ((const float4*)(xi + (size_t)row * T_IN))[tid];
        float urv[4], uiv[4], nn[4];
#pragma unroll
        for (int k = 0; k < 4; ++k) {
            float re = (&r.x)[k], im = (&m.x)[k];
            float a  = fmaf(re, re, im * im);
            float rs = __builtin_amdgcn_rsqf(a);
            bool  z  = !(a > 0.0f);            // angle(0)=0 -> unit (1,0), |s|=0
            nn[k]  = z ? 0.0f : a * rs;
            urv[k] = z ? 1.0f : re * rs;
            uiv[k] = z ? 0.0f : im * rs;
        }
        ((float4*)ur)[tid]  = make_float4(urv[0], urv[1], urv[2], urv[3]);
        ((float4*)uim)[tid] = make_float4(uiv[0], uiv[1], uiv[2], uiv[3]);
        ((float4*)nr)[tid]  = make_float4(nn[0],  nn[1],  nn[2],  nn[3]);
        if (tid == 0) {                        // zero-pad frame 2048
            ur[T_IN] = 1.0f; uim[T_IN] = 0.0f; nr[T_IN] = 0.0f;
        }
    }
    __syncthreads();

    // ---- Chunk: per-output unit rotation c_t and interpolated magnitude ----
    // c_t = unit(s[i0+1]) * conj(unit(s[i0])) at i0 = floor(0.9*(t-1)); c_0 = unit(s[0]).
    // exp(i*phase_acc_t) == prefix product of c_0..c_t (wrapping is free under exp).
    const int base = tid * CHUNK;
    float cr[CHUNK], ci[CHUNK], mg[CHUNK];
    float rr = 1.0f, ri = 0.0f;                // this thread's running product
#pragma unroll
    for (int j = 0; j < CHUNK; ++j) {
        int t = base + j;
        float c_r = 1.0f, c_i = 0.0f, m = 0.0f;
        if (t < T_OUT) {
            float ts    = (float)t * RATE;     // f32 == jnp.arange fill
            int   i0    = (int)ts;
            float alpha = ts - (float)i0;
            float n0 = nr[i0];
            float n1 = nr[i0 + 1];
            m = alpha * n1 + (1.0f - alpha) * n0;
            if (t == 0) {
                c_r = ur[0]; c_i = uim[0];
            } else {
                int   p0 = (int)((float)(t - 1) * RATE);
                float bx = ur[p0],     by = uim[p0];       // frame i0(t-1)
                float ax = ur[p0 + 1], ay = uim[p0 + 1];
                c_r = fmaf(ax, bx,  ay * by);              // a * conj(b)
                c_i = fmaf(ay, bx, -ax * by);
            }
        }
        cr[j] = c_r; ci[j] = c_i; mg[j] = m;
        float tr = fmaf(rr, c_r, -ri * c_i);
        float ti = fmaf(rr, c_i,  ri * c_r);
        rr = tr; ri = ti;
    }

    // renormalize thread total: bounds cross-thread magnitude drift
    {
        float s = __builtin_amdgcn_rsqf(fmaf(rr, rr, ri * ri));
        rr *= s; ri *= s;
    }

    // ---- wave-level inclusive scan (complex product, 6 shuffle steps) ----
#pragma unroll
    for (int off = 1; off < 64; off <<= 1) {
        float or_ = __shfl_up(rr, off);
        float oi_ = __shfl_up(ri, off);
        bool ok = (lane >= off);
        or_ = ok ? or_ : 1.0f;
        oi_ = ok ? oi_ : 0.0f;
        float tr = fmaf(or_, rr, -oi_ * ri);
        float ti = fmaf(or_, ri,  oi_ * rr);
        rr = tr; ri = ti;
    }
    // exclusive prefix within wave
    float er = __shfl_up(rr, 1);
    float ei = __shfl_up(ri, 1);
    if (lane == 0) { er = 1.0f; ei = 0.0f; }
    if (lane == 63) wtot[wid] = make_float2(rr, ri);
    __syncthreads();   // also closes all plane reads -> staging may alias now

    // ---- cross-wave exclusive prefix (uniform per wave) ----
    float pr = er, pi = ei;
#pragma unroll
    for (int w = 0; w < NWAVE; ++w) {
        if (w < wid) {
            float2 wt = wtot[w];
            float tr = fmaf(wt.x, pr, -wt.y * pi);
            float ti = fmaf(wt.x, pi,  wt.y * pr);
            pr = tr; pi = ti;
        }
    }

    // ---- epilogue: per-element inclusive product -> staged re/im ----
#pragma unroll
    for (int j = 0; j < CHUNK; ++j) {
        float tr = fmaf(pr, cr[j], -pi * ci[j]);
        float ti = fmaf(pr, ci[j],  pi * cr[j]);
        pr = tr; pi = ti;
        int t = base + j;
        if (t < T_OUT) {
            st_re[t] = mg[j] * pr;
            st_im[t] = mg[j] * pi;
        }
    }
    __syncthreads();

    // ---- coalesced planar float4 store (nontemporal: output never re-read) ----
    const long long nplane = (long long)n_rows * T_OUT;
    const long long rowb   = (long long)row * T_OUT;
    const v4f* sre4 = (const v4f*)st_re;
    const v4f* sim4 = (const v4f*)st_im;
    for (int v = tid; v < T_OUT / 4; v += NTH) {
        long long o = rowb + 4 * (long long)v;
        if (o + 3 < out_floats)
            __builtin_nontemporal_store(sre4[v], (v4f*)(out + o));
        if (nplane + o + 3 < out_floats)
            __builtin_nontemporal_store(sim4[v], (v4f*)(out + nplane + o));
    }
}

extern "C" void kernel_launch(void* const* d_in, const int* in_sizes, int n_in,
                              void* d_out, int out_size, void* d_ws, size_t ws_size,
                              hipStream_t stream) {
    const float* xr = (const float*)d_in[0];
    const float* xi = (const float*)d_in[1];
    float* out = (float*)d_out;
    const int n_rows = in_sizes[0] / T_IN;     // 16 * 1025 = 16400
    phase_vocoder_kernel<<<n_rows, NTH, 0, stream>>>(xr, xi, out, n_rows,
                                                     (long long)out_size);
}

// Round 7
// 85.687 us; speedup vs baseline: 1.0115x; 1.0115x over previous
//
#include <hip/hip_runtime.h>
#include <math.h>

#define T_IN   2048
#define T_OUT  2276
#define NTH    512
#define CHUNK  5               // 512*5 = 2560 >= 2276
#define NWAVE  (NTH/64)
#define RATE   0.9f

typedef float v4f __attribute__((ext_vector_type(4)));

// LDS: three float planes [ur][ui][nr] (conflict-light b32 reads).
// Output staging ALIASES this region after the post-scan barrier.
#define NFR     2052           // frames 0..2048 used; padded to multiple of 4
#define ST_N    2304           // staging stride (>= T_OUT, 16B aligned)

__global__ __launch_bounds__(NTH, 8)
void phase_vocoder_v7(const float* __restrict__ xr,
                      const float* __restrict__ xi,
                      float* __restrict__ out,
                      int n_rows, long long out_floats)
{
    __shared__ __align__(16) float smem[3 * NFR];
    __shared__ float2 wtot[NWAVE];
    float* ur  = smem;                 // unit-vector real, per input frame
    float* uim = smem + NFR;           // unit-vector imag
    float* nr  = smem + 2 * NFR;       // magnitude
    float* st_re = smem;               // aliases planes after the scan barrier
    float* st_im = smem + ST_N;

    const int row  = blockIdx.x;
    const int tid  = threadIdx.x;
    const int lane = tid & 63;
    const int wid  = tid >> 6;

    // ---- Fill: unit vector + |s| per input frame (float4 loads, b128 LDS writes) ----
    {
        const float4 r = ((const float4*)(xr + (size_t)row * T_IN))[tid];
        const float4 m = ((const float4*)(xi + (size_t)row * T_IN))[tid];
        float urv[4], uiv[4], nn[4];
#pragma unroll
        for (int k = 0; k < 4; ++k) {
            float re = (&r.x)[k], im = (&m.x)[k];
            float a  = fmaf(re, re, im * im);
            float rs = __builtin_amdgcn_rsqf(a);
            bool  z  = !(a > 0.0f);            // angle(0)=0 -> unit (1,0), |s|=0
            nn[k]  = z ? 0.0f : a * rs;
            urv[k] = z ? 1.0f : re * rs;
            uiv[k] = z ? 0.0f : im * rs;
        }
        ((float4*)ur)[tid]  = make_float4(urv[0], urv[1], urv[2], urv[3]);
        ((float4*)uim)[tid] = make_float4(uiv[0], uiv[1], uiv[2], uiv[3]);
        ((float4*)nr)[tid]  = make_float4(nn[0],  nn[1],  nn[2],  nn[3]);
        if (tid == 0) {                        // zero-pad frame 2048
            ur[T_IN] = 1.0f; uim[T_IN] = 0.0f; nr[T_IN] = 0.0f;
        }
    }
    __syncthreads();

    // ---- Chunk: rotation c_t = unit(s[i0+1])*conj(unit(s[i0])), cum-product ----
    // ip caches i0(t-1); bit-identical to recomputing (int)((t-1)*RATE).
    const int   base  = tid * CHUNK;
    const float fbase = (float)base;           // exact: base < 2^24
    float cumr[CHUNK], cumi[CHUNK], mg[CHUNK];
    float rr = 1.0f, ri = 0.0f;
    int ip = (base > 0) ? (int)((fbase - 1.0f) * RATE) : 0;   // i0 of t-1
#pragma unroll
    for (int j = 0; j < CHUNK; ++j) {
        int t = base + j;
        float c_r = 1.0f, c_i = 0.0f, m = 0.0f;
        if (t < T_OUT) {
            float ts    = (fbase + (float)j) * RATE;   // == (float)t * RATE bitwise
            int   i0    = (int)ts;
            float alpha = ts - (float)i0;
            float n0 = nr[i0];
            float n1 = nr[i0 + 1];
            m = alpha * n1 + (1.0f - alpha) * n0;
            if (t == 0) {
                c_r = ur[0]; c_i = uim[0];
            } else {
                float bx = ur[ip],     by = uim[ip];       // frame i0(t-1)
                float ax = ur[ip + 1], ay = uim[ip + 1];
                c_r = fmaf(ax, bx,  ay * by);              // a * conj(b)
                c_i = fmaf(ay, bx, -ax * by);
            }
            ip = i0;
        }
        float tr = fmaf(rr, c_r, -ri * c_i);
        float ti = fmaf(rr, c_i,  ri * c_r);
        rr = tr; ri = ti;
        cumr[j] = rr; cumi[j] = ri; mg[j] = m;   // cum saved -> ILP epilogue
    }

    // renormalize thread total: bounds cross-thread magnitude drift
    {
        float s = __builtin_amdgcn_rsqf(fmaf(rr, rr, ri * ri));
        rr *= s; ri *= s;
    }

    // ---- wave-level inclusive scan (complex product, 6 shuffle steps) ----
#pragma unroll
    for (int off = 1; off < 64; off <<= 1) {
        float or_ = __shfl_up(rr, off);
        float oi_ = __shfl_up(ri, off);
        bool ok = (lane >= off);
        or_ = ok ? or_ : 1.0f;
        oi_ = ok ? oi_ : 0.0f;
        float tr = fmaf(or_, rr, -oi_ * ri);
        float ti = fmaf(or_, ri,  oi_ * rr);
        rr = tr; ri = ti;
    }
    // exclusive prefix within wave
    float er = __shfl_up(rr, 1);
    float ei = __shfl_up(ri, 1);
    if (lane == 0) { er = 1.0f; ei = 0.0f; }
    if (lane == 63) wtot[wid] = make_float2(rr, ri);
    __syncthreads();   // also closes all plane reads -> staging may alias now

    // ---- cross-wave exclusive prefix (uniform per wave) ----
    float pr = er, pi = ei;
#pragma unroll
    for (int w = 0; w < NWAVE; ++w) {
        if (w < wid) {
            float2 wt = wtot[w];
            float tr = fmaf(wt.x, pr, -wt.y * pi);
            float ti = fmaf(wt.x, pi,  wt.y * pr);
            pr = tr; pi = ti;
        }
    }

    // ---- epilogue: independent prefix-apply (no serial chain) -> staged re/im ----
#pragma unroll
    for (int j = 0; j < CHUNK; ++j) {
        int t = base + j;
        if (t < T_OUT) {
            float orr = fmaf(pr, cumr[j], -pi * cumi[j]);
            float oii = fmaf(pr, cumi[j],  pi * cumr[j]);
            st_re[t] = mg[j] * orr;
            st_im[t] = mg[j] * oii;
        }
    }
    __syncthreads();

    // ---- coalesced planar float4 store (round-3 proven path: guards kept) ----
    const long long nplane = (long long)n_rows * T_OUT;
    const long long rowb   = (long long)row * T_OUT;
    const v4f* sre4 = (const v4f*)st_re;
    const v4f* sim4 = (const v4f*)st_im;
    for (int v = tid; v < T_OUT / 4; v += NTH) {
        long long o = rowb + 4 * (long long)v;
        if (o + 3 < out_floats)
            __builtin_nontemporal_store(sre4[v], (v4f*)(out + o));
        if (nplane + o + 3 < out_floats)
            __builtin_nontemporal_store(sim4[v], (v4f*)(out + nplane + o));
    }
}

extern "C" void kernel_launch(void* const* d_in, const int* in_sizes, int n_in,
                              void* d_out, int out_size, void* d_ws, size_t ws_size,
                              hipStream_t stream) {
    const float* xr = (const float*)d_in[0];
    const float* xi = (const float*)d_in[1];
    float* out = (float*)d_out;
    const int n_rows = in_sizes[0] / T_IN;     // 16 * 1025 = 16400
    phase_vocoder_v7<<<n_rows, NTH, 0, stream>>>(xr, xi, out, n_rows,
                                                 (long long)out_size);
}